// Round 1
// baseline (305.495 us; speedup 1.0000x reference)
//
#include <hip/hip_runtime.h>
#include <hip/hip_bf16.h>
#include <math.h>

// Problem: B=8, T=2048, E=1024, D=64. Inputs (fp32): x[B,T,E], Wk[D,E], Wq[D,E], Wv[D,E].
// out fp32 [B,T,D]. Workspace: q,k bf16 [B*T,64]; vT bf16 [B,64,T]. 6 MB total.

typedef __bf16 bf16x8 __attribute__((ext_vector_type(8)));
typedef float  f32x4  __attribute__((ext_vector_type(4)));

#define M_TOT 16384   // B*T
#define E_DIM 1024
#define D_HEAD 64
#define T_SEQ 2048

__device__ __forceinline__ unsigned short f2b(float f) {
  union { float f; unsigned int u; } cv; cv.f = f;
  unsigned int u = cv.u;
  u += 0x7FFFu + ((u >> 16) & 1u);   // RTNE
  return (unsigned short)(u >> 16);
}

// XOR swizzle: 64-col bf16 tiles, 8 groups of 8 cols; physical group = g ^ (row&7).
// Staging writes 4-elem chunks (g = c4>>1, h = c4&1); frag reads 8-elem groups.
__device__ __forceinline__ int swz_chunk(int row, int c4) {
  int g = c4 >> 1, h = c4 & 1;
  return row * 64 + ((g ^ (row & 7)) << 3) + h * 4;
}
__device__ __forceinline__ int swz_grp(int row, int g) {
  return row * 64 + ((g ^ (row & 7)) << 3);
}

// ---------------------------------------------------------------------------
// Projection: C[16384 x 192] = x[16384 x 1024] * W^T, W rows: 0-63 Wq, 64-127 Wk, 128-191 Wv
// Block: 256 thr, BM=64 rows, full N=192, BK=64. Grid: 256 blocks.
// ---------------------------------------------------------------------------
__global__ __launch_bounds__(256) void proj_kernel(
    const float* __restrict__ x, const float* __restrict__ Wk,
    const float* __restrict__ Wq, const float* __restrict__ Wv,
    unsigned short* __restrict__ qws, unsigned short* __restrict__ kws,
    unsigned short* __restrict__ vtws)
{
  __shared__ unsigned short x_lds[64 * 64];
  __shared__ unsigned short w_lds[192 * 64];

  const int tid  = threadIdx.x;
  const int wv   = tid >> 6;
  const int lane = tid & 63;
  const int c    = lane & 15;
  const int quad = lane >> 4;
  const int row0 = blockIdx.x * 64;

  f32x4 acc[12];
  for (int nt = 0; nt < 12; ++nt)
    for (int r = 0; r < 4; ++r) acc[nt][r] = 0.0f;

  for (int step = 0; step < 16; ++step) {
    const int k0 = step * 64;
    __syncthreads();
    // stage x tile: 64 rows x 64 cols fp32 -> bf16, 1024 float4 chunks
    for (int i = tid; i < 1024; i += 256) {
      int r = i >> 4, c4 = i & 15;
      float4 v = *(const float4*)(x + (row0 + r) * E_DIM + k0 + c4 * 4);
      ushort4 u = make_ushort4(f2b(v.x), f2b(v.y), f2b(v.z), f2b(v.w));
      *(ushort4*)&x_lds[swz_chunk(r, c4)] = u;
    }
    // stage W tile: 192 rows x 64 cols
    for (int i = tid; i < 3072; i += 256) {
      int n = i >> 4, c4 = i & 15;
      const float* wp = (n < 64) ? (Wq + n * E_DIM)
                      : (n < 128) ? (Wk + (n - 64) * E_DIM)
                                  : (Wv + (n - 128) * E_DIM);
      float4 v = *(const float4*)(wp + k0 + c4 * 4);
      ushort4 u = make_ushort4(f2b(v.x), f2b(v.y), f2b(v.z), f2b(v.w));
      *(ushort4*)&w_lds[swz_chunk(n, c4)] = u;
    }
    __syncthreads();
    // MFMA: wave wv owns m-tile wv (rows wv*16..+15), all 12 n-tiles
    const int m = wv * 16 + c;
    for (int ks = 0; ks < 2; ++ks) {
      bf16x8 a = *(const bf16x8*)&x_lds[swz_grp(m, ks * 4 + quad)];
      for (int nt = 0; nt < 12; ++nt) {
        int n = nt * 16 + c;
        bf16x8 bb = *(const bf16x8*)&w_lds[swz_grp(n, ks * 4 + quad)];
        acc[nt] = __builtin_amdgcn_mfma_f32_16x16x32_bf16(a, bb, acc[nt], 0, 0, 0);
      }
    }
  }

  // epilogue: C rows = row0 + wv*16 + quad*4 + reg, col = lane&15 within tile
  const int rbase = row0 + wv * 16 + quad * 4;
  for (int nt = 0; nt < 12; ++nt) {
    int dd = (nt & 3) * 16 + c;
    if (nt < 4) {
      for (int r = 0; r < 4; ++r)
        qws[(rbase + r) * D_HEAD + dd] = f2b(acc[nt][r]);
    } else if (nt < 8) {
      for (int r = 0; r < 4; ++r)
        kws[(rbase + r) * D_HEAD + dd] = f2b(acc[nt][r]);
    } else {
      int bb = rbase >> 11, tt = rbase & 2047;   // 4 regs = 4 consecutive t
      ushort4 u = make_ushort4(f2b(acc[nt][0]), f2b(acc[nt][1]),
                               f2b(acc[nt][2]), f2b(acc[nt][3]));
      *(ushort4*)&vtws[bb * (D_HEAD * T_SEQ) + dd * T_SEQ + tt] = u;
    }
  }
}

// ---------------------------------------------------------------------------
// Flash attention: block per (qt, b). BM=BN=64, D=64. 256 thr = 4 waves,
// wave wv owns q-rows wv*16..+15. Online softmax in registers
// (row = quad*4+reg C-layout; reduce across the 16-lane group via shfl_xor).
// ---------------------------------------------------------------------------
__global__ __launch_bounds__(256) void attn_kernel(
    const unsigned short* __restrict__ qws, const unsigned short* __restrict__ kws,
    const unsigned short* __restrict__ vtws, float* __restrict__ out)
{
  __shared__ unsigned short q_lds[64 * 64];
  __shared__ unsigned short k_lds[64 * 64];
  __shared__ unsigned short vt_lds[64 * 64];
  __shared__ unsigned short p_lds[64 * 64];

  const int tid  = threadIdx.x;
  const int wv   = tid >> 6;
  const int lane = tid & 63;
  const int c    = lane & 15;
  const int quad = lane >> 4;
  const int qt   = blockIdx.x;
  const int b    = blockIdx.y;
  const int t0   = qt * 64;
  const int qkbase = b * (T_SEQ * D_HEAD);

  // stage Q tile (bf16 from ws)
  for (int i = tid; i < 1024; i += 256) {
    int r = i >> 4, c4 = i & 15;
    ushort4 u = *(const ushort4*)(qws + qkbase + (t0 + r) * D_HEAD + c4 * 4);
    *(ushort4*)&q_lds[swz_chunk(r, c4)] = u;
  }

  float m_st[4], l_st[4];
  f32x4 acc_o[4];
  for (int r = 0; r < 4; ++r) { m_st[r] = -__builtin_inff(); l_st[r] = 0.0f; }
  for (int nt = 0; nt < 4; ++nt)
    for (int r = 0; r < 4; ++r) acc_o[nt][r] = 0.0f;

  const int m    = wv * 16 + c;        // A-operand row (frag reads)
  const int rloc = wv * 16 + quad * 4; // +reg = C-layout row (local)

  for (int kt = 0; kt <= qt; ++kt) {
    const int s0 = kt * 64;
    __syncthreads();   // prior iter's LDS reads done (also covers Q staging on iter 0)
    // stage K tile
    for (int i = tid; i < 1024; i += 256) {
      int r = i >> 4, c4 = i & 15;
      ushort4 u = *(const ushort4*)(kws + qkbase + (s0 + r) * D_HEAD + c4 * 4);
      *(ushort4*)&k_lds[swz_chunk(r, c4)] = u;
    }
    // stage V^T tile: rows d (64), cols s-local (64)
    for (int i = tid; i < 1024; i += 256) {
      int d = i >> 4, c4 = i & 15;
      ushort4 u = *(const ushort4*)(vtws + b * (D_HEAD * T_SEQ) + d * T_SEQ + s0 + c4 * 4);
      *(ushort4*)&vt_lds[swz_chunk(d, c4)] = u;
    }
    __syncthreads();

    // S = Q K^T (scaled)
    f32x4 accs[4];
    for (int nt = 0; nt < 4; ++nt)
      for (int r = 0; r < 4; ++r) accs[nt][r] = 0.0f;
    for (int ks = 0; ks < 2; ++ks) {
      bf16x8 a = *(const bf16x8*)&q_lds[swz_grp(m, ks * 4 + quad)];
      for (int nt = 0; nt < 4; ++nt) {
        int n = nt * 16 + c;
        bf16x8 bb = *(const bf16x8*)&k_lds[swz_grp(n, ks * 4 + quad)];
        accs[nt] = __builtin_amdgcn_mfma_f32_16x16x32_bf16(a, bb, accs[nt], 0, 0, 0);
      }
    }
    for (int nt = 0; nt < 4; ++nt)
      for (int r = 0; r < 4; ++r) accs[nt][r] *= 0.125f;   // 1/sqrt(64)
    if (kt == qt) {   // diagonal tile: causal mask
      for (int nt = 0; nt < 4; ++nt) {
        int scol = s0 + nt * 16 + c;
        for (int r = 0; r < 4; ++r)
          if (scol > t0 + rloc + r) accs[nt][r] = -__builtin_inff();
      }
    }

    // online softmax (state per C-row, reduced over the 16-lane group)
    float mx[4];
    for (int r = 0; r < 4; ++r)
      mx[r] = fmaxf(fmaxf(accs[0][r], accs[1][r]), fmaxf(accs[2][r], accs[3][r]));
    for (int off = 1; off < 16; off <<= 1)
      for (int r = 0; r < 4; ++r)
        mx[r] = fmaxf(mx[r], __shfl_xor(mx[r], off));
    float alpha[4], rsum[4];
    for (int r = 0; r < 4; ++r) {
      float mnew = fmaxf(m_st[r], mx[r]);
      alpha[r] = __expf(m_st[r] - mnew);   // first iter: exp(-inf)=0
      m_st[r] = mnew;
      rsum[r] = 0.0f;
    }
    for (int nt = 0; nt < 4; ++nt)
      for (int r = 0; r < 4; ++r) {
        float p = __expf(accs[nt][r] - m_st[r]);   // masked: exp(-inf)=0
        accs[nt][r] = p;
        rsum[r] += p;
      }
    for (int off = 1; off < 16; off <<= 1)
      for (int r = 0; r < 4; ++r)
        rsum[r] += __shfl_xor(rsum[r], off);
    for (int r = 0; r < 4; ++r)
      l_st[r] = alpha[r] * l_st[r] + rsum[r];
    for (int nt = 0; nt < 4; ++nt)
      for (int r = 0; r < 4; ++r) acc_o[nt][r] *= alpha[r];

    // P -> LDS (bf16, swizzled) for PV A-operand
    for (int nt = 0; nt < 4; ++nt) {
      for (int r = 0; r < 4; ++r) {
        int col = nt * 16 + c, rr = rloc + r;
        p_lds[rr * 64 + (((col >> 3) ^ (rr & 7)) << 3) + (col & 7)] = f2b(accs[nt][r]);
      }
    }
    __syncthreads();

    // O += P V   (B-operand from V^T rows = contiguous)
    for (int ks = 0; ks < 2; ++ks) {
      bf16x8 a = *(const bf16x8*)&p_lds[swz_grp(m, ks * 4 + quad)];
      for (int nt = 0; nt < 4; ++nt) {
        int n = nt * 16 + c;
        bf16x8 vv = *(const bf16x8*)&vt_lds[swz_grp(n, ks * 4 + quad)];
        acc_o[nt] = __builtin_amdgcn_mfma_f32_16x16x32_bf16(a, vv, acc_o[nt], 0, 0, 0);
      }
    }
  }

  // epilogue: O / l  -> out fp32 [B,T,D]
  for (int nt = 0; nt < 4; ++nt) {
    for (int r = 0; r < 4; ++r) {
      int t = t0 + rloc + r;
      out[qkbase + t * D_HEAD + nt * 16 + c] = acc_o[nt][r] / l_st[r];
    }
  }
}

extern "C" void kernel_launch(void* const* d_in, const int* in_sizes, int n_in,
                              void* d_out, int out_size, void* d_ws, size_t ws_size,
                              hipStream_t stream) {
  // setup_inputs order: x, Wk, Wq, Wv
  const float* x  = (const float*)d_in[0];
  const float* Wk = (const float*)d_in[1];
  const float* Wq = (const float*)d_in[2];
  const float* Wv = (const float*)d_in[3];
  float* out = (float*)d_out;

  unsigned short* qws  = (unsigned short*)d_ws;
  unsigned short* kws  = qws + (size_t)M_TOT * D_HEAD;
  unsigned short* vtws = kws + (size_t)M_TOT * D_HEAD;

  proj_kernel<<<M_TOT / 64, 256, 0, stream>>>(x, Wk, Wq, Wv, qws, kws, vtws);
  attn_kernel<<<dim3(T_SEQ / 64, 8), 256, 0, stream>>>(qws, kws, vtws, out);
}

// Round 2
// 144.836 us; speedup vs baseline: 2.1093x; 2.1093x over previous
//
#include <hip/hip_runtime.h>
#include <hip/hip_bf16.h>

// B=8, T=2048, E=1024, D=64. in: x fp32[B,T,E], Wk/Wq/Wv fp32[64,1024]. out fp32[B,T,64].
// ws: qws/kws bf16[16384,64], vtws bf16[8,64,2048], Wb bf16[192,1024],
//     opart fp32[2][16384,64], mpart/lpart fp32[2][16384]  (~14.7 MB)

typedef __bf16 bf16x8 __attribute__((ext_vector_type(8)));
typedef float  f32x4  __attribute__((ext_vector_type(4)));

#define T_SEQ 2048
#define E_DIM 1024
#define D_HEAD 64
#define M_TOT 16384

__device__ __forceinline__ unsigned short f2b(float f) {
  union { float f; unsigned int u; } cv; cv.f = f;
  unsigned int u = cv.u;
  u += 0x7FFFu + ((u >> 16) & 1u);   // RTNE
  return (unsigned short)(u >> 16);
}

// async 16B global->LDS (lds dest = wave-uniform base + lane*16)
__device__ __forceinline__ void dma16(const unsigned short* g, unsigned short* l) {
  __builtin_amdgcn_global_load_lds(
      (const __attribute__((address_space(1))) void*)g,
      (__attribute__((address_space(3))) void*)l, 16, 0, 0);
}

// ---------------------------------------------------------------------------
// W fp32 -> bf16, packed rows: 0-63 Wq, 64-127 Wk, 128-191 Wv
// ---------------------------------------------------------------------------
__global__ __launch_bounds__(256) void wcvt_kernel(
    const float* __restrict__ Wk, const float* __restrict__ Wq,
    const float* __restrict__ Wv, unsigned short* __restrict__ Wb)
{
  int i = blockIdx.x * 256 + threadIdx.x;      // 49152 float4 chunks
  int n = i >> 8, c4 = i & 255;
  const float* src = (n < 64) ? Wq + n * E_DIM
                   : (n < 128) ? Wk + (n - 64) * E_DIM
                               : Wv + (n - 128) * E_DIM;
  float4 v = *(const float4*)(src + c4 * 4);
  *(ushort4*)(Wb + (size_t)n * E_DIM + c4 * 4) =
      make_ushort4(f2b(v.x), f2b(v.y), f2b(v.z), f2b(v.w));
}

// ---------------------------------------------------------------------------
// proj: [16384 x 192] = x * Wb^T. BM=32, BK=128, grid 512, 4 waves.
// wave: m-tile = wv&1, n-half = wv>>1 (6 n-tiles). W staged by DMA (bf16),
// x staged via cvt. 16B XOR swizzle (phys_chunk = g ^ (row&7)) both tiles.
// ---------------------------------------------------------------------------
__global__ __launch_bounds__(256) void proj_kernel(
    const float* __restrict__ x, const unsigned short* __restrict__ Wb,
    unsigned short* __restrict__ qws, unsigned short* __restrict__ kws,
    unsigned short* __restrict__ vtws)
{
  __shared__ unsigned short x_lds[32 * 128];    // 8 KB
  __shared__ unsigned short w_lds[192 * 128];   // 48 KB

  const int tid = threadIdx.x, wv = tid >> 6, lane = tid & 63;
  const int c = lane & 15, quad = lane >> 4;
  const int row0 = blockIdx.x * 32;
  const int mi = wv & 1, nh = wv >> 1;

  f32x4 acc[6];
  for (int j = 0; j < 6; ++j)
    for (int r = 0; r < 4; ++r) acc[j][r] = 0.0f;

  for (int step = 0; step < 8; ++step) {
    const int k0 = step * 128;
    __syncthreads();
    // x: 32x128 fp32 -> bf16 LDS, 1024 half-chunks (8B each)
    for (int jj = 0; jj < 4; ++jj) {
      int idx = tid + jj * 256;
      int r = idx >> 5, h = idx & 31;
      float4 v = *(const float4*)(x + (size_t)(row0 + r) * E_DIM + k0 + h * 4);
      int pc = (h >> 1) ^ (r & 7);
      *(ushort4*)&x_lds[r * 128 + pc * 8 + (h & 1) * 4] =
          make_ushort4(f2b(v.x), f2b(v.y), f2b(v.z), f2b(v.w));
    }
    // W: 192x128 bf16 via DMA, 3072 chunks, global-side swizzle
    for (int j = 0; j < 12; ++j) {
      int base = (wv * 12 + j) * 64;
      int p = base + lane;
      int n = p >> 4, pg = p & 15, g = pg ^ (n & 7);
      dma16(Wb + (size_t)n * E_DIM + k0 + g * 8, &w_lds[base * 8]);
    }
    __syncthreads();
    const int m = mi * 16 + c;
    for (int ks = 0; ks < 4; ++ks) {
      int ga = (ks * 4 + quad) ^ (m & 7);
      bf16x8 a = *(const bf16x8*)&x_lds[m * 128 + ga * 8];
      for (int j = 0; j < 6; ++j) {
        int n = (nh * 6 + j) * 16 + c;
        int gb = (ks * 4 + quad) ^ (n & 7);
        bf16x8 bb = *(const bf16x8*)&w_lds[n * 128 + gb * 8];
        acc[j] = __builtin_amdgcn_mfma_f32_16x16x32_bf16(a, bb, acc[j], 0, 0, 0);
      }
    }
  }

  const int rbase = row0 + mi * 16 + quad * 4;
  for (int j = 0; j < 6; ++j) {
    int nt = nh * 6 + j;
    if (nt < 4) {
      int d = nt * 16 + c;
      for (int r = 0; r < 4; ++r) qws[(size_t)(rbase + r) * D_HEAD + d] = f2b(acc[j][r]);
    } else if (nt < 8) {
      int d = (nt - 4) * 16 + c;
      for (int r = 0; r < 4; ++r) kws[(size_t)(rbase + r) * D_HEAD + d] = f2b(acc[j][r]);
    } else {
      int d = (nt - 8) * 16 + c;
      int bb = rbase >> 11, tt = rbase & 2047;
      *(ushort4*)&vtws[(size_t)bb * D_HEAD * T_SEQ + (size_t)d * T_SEQ + tt] =
          make_ushort4(f2b(acc[j][0]), f2b(acc[j][1]), f2b(acc[j][2]), f2b(acc[j][3]));
    }
  }
}

// ---------------------------------------------------------------------------
// attn: block=(qt, b, sg). sg in {0,1} takes s-superblocks (128 wide) of its
// parity. BN=128 per iter, 4 waves x 16 q-rows. Unnormalized O + m,l partials.
// exp2 domain (scale*log2e folded). p_lds rows are wave-private (no barrier).
// ---------------------------------------------------------------------------
__global__ __launch_bounds__(256) void attn_kernel(
    const unsigned short* __restrict__ qws, const unsigned short* __restrict__ kws,
    const unsigned short* __restrict__ vtws,
    float* __restrict__ opart, float* __restrict__ mpart, float* __restrict__ lpart)
{
  __shared__ unsigned short q_lds[64 * 64];     // 8 KB
  __shared__ unsigned short k_lds[128 * 64];    // 16 KB
  __shared__ unsigned short vt_lds[64 * 128];   // 16 KB
  __shared__ unsigned short p_lds[64 * 128];    // 16 KB

  const int tid = threadIdx.x, wv = tid >> 6, lane = tid & 63;
  const int c = lane & 15, quad = lane >> 4;
  const int qt = blockIdx.x, b = blockIdx.y, sg = blockIdx.z;
  const int t0 = qt * 64;
  const size_t qkbase = (size_t)b * T_SEQ * D_HEAD;
  const int ssmax = qt >> 1;
  const int niter = (ssmax >= sg) ? ((ssmax - sg) >> 1) + 1 : 0;
  const int rloc = wv * 16 + quad * 4;
  const size_t prow = ((size_t)sg * 8 + b) * T_SEQ;   // row base in partial arrays

  if (niter == 0) {   // no work: zero partial, m=-inf, l=0
    for (int nt = 0; nt < 4; ++nt)
      for (int r = 0; r < 4; ++r)
        opart[(prow + t0 + rloc + r) * D_HEAD + nt * 16 + c] = 0.0f;
    if (c == 0)
      for (int r = 0; r < 4; ++r) {
        mpart[prow + t0 + rloc + r] = -__builtin_inff();
        lpart[prow + t0 + rloc + r] = 0.0f;
      }
    return;
  }

  // Q tile DMA (once)
  for (int j = 0; j < 2; ++j) {
    int base = (wv * 2 + j) * 64;
    int p = base + lane;
    int r = p >> 3, pg = p & 7, g = pg ^ (r & 7);
    dma16(qws + qkbase + (size_t)(t0 + r) * D_HEAD + g * 8, &q_lds[base * 8]);
  }

  float m_st[4], l_st[4];
  f32x4 acc_o[4];
  for (int r = 0; r < 4; ++r) { m_st[r] = -__builtin_inff(); l_st[r] = 0.0f; }
  for (int nt = 0; nt < 4; ++nt)
    for (int r = 0; r < 4; ++r) acc_o[nt][r] = 0.0f;

  const float sc = 0.18033688011112042f;   // (1/8) * log2(e)
  const int m_row = wv * 16 + c;

  for (int it = 0; it < niter; ++it) {
    const int ss = sg + 2 * it;
    const int s0 = ss * 128;
    __syncthreads();
    // K tile: 128 rows x 64 d
    for (int j = 0; j < 4; ++j) {
      int base = (wv * 4 + j) * 64;
      int p = base + lane;
      int r = p >> 3, pg = p & 7, g = pg ^ (r & 7);
      dma16(kws + qkbase + (size_t)(s0 + r) * D_HEAD + g * 8, &k_lds[base * 8]);
    }
    // V^T tile: 64 rows(d) x 128 s
    for (int j = 0; j < 4; ++j) {
      int base = (wv * 4 + j) * 64;
      int p = base + lane;
      int r = p >> 4, pg = p & 15, g = pg ^ (r & 7);
      dma16(vtws + (size_t)b * D_HEAD * T_SEQ + (size_t)r * T_SEQ + s0 + g * 8,
            &vt_lds[base * 8]);
    }
    __syncthreads();

    // S = Q K^T (exp2 domain)
    f32x4 accs[8];
    for (int nt = 0; nt < 8; ++nt)
      for (int r = 0; r < 4; ++r) accs[nt][r] = 0.0f;
    for (int ks = 0; ks < 2; ++ks) {
      int ga = (ks * 4 + quad) ^ (m_row & 7);
      bf16x8 a = *(const bf16x8*)&q_lds[m_row * 64 + ga * 8];
      for (int nt = 0; nt < 8; ++nt) {
        int n = nt * 16 + c;
        int gb = (ks * 4 + quad) ^ (n & 7);
        bf16x8 bb = *(const bf16x8*)&k_lds[n * 64 + gb * 8];
        accs[nt] = __builtin_amdgcn_mfma_f32_16x16x32_bf16(a, bb, accs[nt], 0, 0, 0);
      }
    }
    for (int nt = 0; nt < 8; ++nt)
      for (int r = 0; r < 4; ++r) accs[nt][r] *= sc;
    if (ss == ssmax) {   // diagonal superblock: causal mask
      for (int nt = 0; nt < 8; ++nt) {
        int scol = s0 + nt * 16 + c;
        for (int r = 0; r < 4; ++r)
          if (scol > t0 + rloc + r) accs[nt][r] = -__builtin_inff();
      }
    }

    // online softmax over 128 cols (reduce across 16-lane group)
    float mx[4];
    for (int r = 0; r < 4; ++r) {
      float v = accs[0][r];
      for (int nt = 1; nt < 8; ++nt) v = fmaxf(v, accs[nt][r]);
      mx[r] = v;
    }
    for (int off = 1; off < 16; off <<= 1)
      for (int r = 0; r < 4; ++r) mx[r] = fmaxf(mx[r], __shfl_xor(mx[r], off));
    float alpha[4], rsum[4];
    for (int r = 0; r < 4; ++r) {
      float mnew = fmaxf(m_st[r], mx[r]);
      alpha[r] = __builtin_exp2f(m_st[r] - mnew);
      m_st[r] = mnew;
      rsum[r] = 0.0f;
    }
    for (int nt = 0; nt < 8; ++nt)
      for (int r = 0; r < 4; ++r) {
        float p = __builtin_exp2f(accs[nt][r] - m_st[r]);
        accs[nt][r] = p;
        rsum[r] += p;
      }
    for (int off = 1; off < 16; off <<= 1)
      for (int r = 0; r < 4; ++r) rsum[r] += __shfl_xor(rsum[r], off);
    for (int r = 0; r < 4; ++r) l_st[r] = alpha[r] * l_st[r] + rsum[r];
    for (int nt = 0; nt < 4; ++nt)
      for (int r = 0; r < 4; ++r) acc_o[nt][r] *= alpha[r];

    // P -> LDS (rows wave-private: no barrier needed)
    for (int nt = 0; nt < 8; ++nt)
      for (int r = 0; r < 4; ++r) {
        int col = nt * 16 + c, rr = rloc + r;
        int pc = (col >> 3) ^ (rr & 7);
        p_lds[rr * 128 + pc * 8 + (col & 7)] = f2b(accs[nt][r]);
      }

    // O += P V
    for (int ks = 0; ks < 4; ++ks) {
      int ga = (ks * 4 + quad) ^ (m_row & 7);
      bf16x8 a = *(const bf16x8*)&p_lds[m_row * 128 + ga * 8];
      for (int nt = 0; nt < 4; ++nt) {
        int n = nt * 16 + c;
        int gb = (ks * 4 + quad) ^ (n & 7);
        bf16x8 vv = *(const bf16x8*)&vt_lds[n * 128 + gb * 8];
        acc_o[nt] = __builtin_amdgcn_mfma_f32_16x16x32_bf16(a, vv, acc_o[nt], 0, 0, 0);
      }
    }
  }

  // epilogue: unnormalized O + m,l
  for (int nt = 0; nt < 4; ++nt)
    for (int r = 0; r < 4; ++r)
      opart[(prow + t0 + rloc + r) * D_HEAD + nt * 16 + c] = acc_o[nt][r];
  if (c == 0)
    for (int r = 0; r < 4; ++r) {
      mpart[prow + t0 + rloc + r] = m_st[r];
      lpart[prow + t0 + rloc + r] = l_st[r];
    }
}

// ---------------------------------------------------------------------------
// merge the 2 partials
// ---------------------------------------------------------------------------
__global__ __launch_bounds__(256) void merge_kernel(
    const float* __restrict__ opart, const float* __restrict__ mpart,
    const float* __restrict__ lpart, float* __restrict__ out)
{
  int gid = blockIdx.x * 256 + threadIdx.x;   // 262144
  int gr = gid >> 4, q4 = gid & 15;
  float m0 = mpart[gr], m1 = mpart[M_TOT + gr];
  float l0 = lpart[gr], l1 = lpart[M_TOT + gr];
  float M = fmaxf(m0, m1);
  float w0 = __builtin_exp2f(m0 - M);
  float w1 = __builtin_exp2f(m1 - M);
  float inv = 1.0f / (w0 * l0 + w1 * l1);
  const float4 o0 = *(const float4*)(opart + (size_t)gr * D_HEAD + q4 * 4);
  const float4 o1 = *(const float4*)(opart + (size_t)M_TOT * D_HEAD + (size_t)gr * D_HEAD + q4 * 4);
  float4 o;
  o.x = (w0 * o0.x + w1 * o1.x) * inv;
  o.y = (w0 * o0.y + w1 * o1.y) * inv;
  o.z = (w0 * o0.z + w1 * o1.z) * inv;
  o.w = (w0 * o0.w + w1 * o1.w) * inv;
  *(float4*)(out + (size_t)gr * D_HEAD + q4 * 4) = o;
}

extern "C" void kernel_launch(void* const* d_in, const int* in_sizes, int n_in,
                              void* d_out, int out_size, void* d_ws, size_t ws_size,
                              hipStream_t stream) {
  const float* x  = (const float*)d_in[0];
  const float* Wk = (const float*)d_in[1];
  const float* Wq = (const float*)d_in[2];
  const float* Wv = (const float*)d_in[3];
  float* out = (float*)d_out;

  unsigned short* qws  = (unsigned short*)d_ws;
  unsigned short* kws  = qws + (size_t)M_TOT * D_HEAD;       // +1M
  unsigned short* vtws = kws + (size_t)M_TOT * D_HEAD;       // +2M
  unsigned short* Wb   = vtws + (size_t)M_TOT * D_HEAD;      // +3M (192K elems)
  float* opart = (float*)(Wb + 192 * E_DIM);                 // 2 x 1M floats
  float* mpart = opart + 2 * (size_t)M_TOT * D_HEAD;         // 2 x 16384
  float* lpart = mpart + 2 * (size_t)M_TOT;                  // 2 x 16384

  wcvt_kernel<<<192, 256, 0, stream>>>(Wk, Wq, Wv, Wb);
  proj_kernel<<<M_TOT / 32, 256, 0, stream>>>(x, Wb, qws, kws, vtws);
  attn_kernel<<<dim3(T_SEQ / 64, 8, 2), 256, 0, stream>>>(qws, kws, vtws, opart, mpart, lpart);
  merge_kernel<<<M_TOT * 16 / 256, 256, 0, stream>>>(opart, mpart, lpart, out);
}